// Round 1
// baseline (262.914 us; speedup 1.0000x reference)
//
#include <hip/hip_runtime.h>
#include <math.h>

// out[h][i][j] = |j - i| * m,  m = alpha[h] if (i==0 || j==0)
//                                 gamma[h] if j > i
//                                 beta[h]  if j < i   (i==j -> dist=0)
//
// Write-only, memory-bound. Persistent grid-stride blocks: 2048 blocks x 256
// threads, each block owns full rows (row = h*S + i), 16 rows/block at
// S=2048. Amortizes wave-launch + kernarg/scalar-load latency over 32
// float4 stores per thread (vs 2 in the one-block-per-row version).

__global__ __launch_bounds__(256) void bidirectional_alibi_kernel(
    const float* __restrict__ alpha,
    const float* __restrict__ beta,
    const float* __restrict__ gamma,
    float* __restrict__ out,
    int S, int nrows)
{
    const int n4 = S >> 2;

    for (int row = blockIdx.x; row < nrows; row += gridDim.x) {
        const int i = row % S;       // block-uniform -> scalar div, once per 8 KB row
        const int h = row / S;
        const float a = alpha[h];
        const float b = beta[h];
        const float g = gamma[h];
        const float fi = (float)i;
        float* __restrict__ rp = out + (size_t)row * (size_t)S;

        if (i == 0) {
            // Entire row is edge: val = a * j  (uniform branch)
            for (int t = threadIdx.x; t < n4; t += 256) {
                const float fj0 = (float)(t << 2);
                float4 v;
                v.x = fj0 * a;
                v.y = (fj0 + 1.0f) * a;
                v.z = (fj0 + 2.0f) * a;
                v.w = (fj0 + 3.0f) * a;
                ((float4*)rp)[t] = v;
            }
        } else {
            for (int t = threadIdx.x; t < n4; t += 256) {
                const int j0 = t << 2;
                float4 v;
                float* vp = (float*)&v;
                #pragma unroll
                for (int k = 0; k < 4; ++k) {
                    const int j = j0 + k;
                    const float fj = (float)j;
                    const float dist = fabsf(fj - fi);
                    const float sel = (j > i) ? g : b;
                    vp[k] = dist * sel;
                }
                if (t == 0) vp[0] = fi * a;   // j==0 edge column (single override)
                ((float4*)rp)[t] = v;
            }
        }

        // Scalar tail if S % 4 != 0 (not hit for S=2048)
        for (int j = (n4 << 2) + (int)threadIdx.x; j < S; j += 256) {
            const float dist = fabsf((float)j - fi);
            float sel = (j > i) ? g : b;
            if (i == 0 || j == 0) sel = a;
            rp[j] = dist * sel;
        }
    }
}

extern "C" void kernel_launch(void* const* d_in, const int* in_sizes, int n_in,
                              void* d_out, int out_size, void* d_ws, size_t ws_size,
                              hipStream_t stream) {
    const float* alpha = (const float*)d_in[0];
    const float* beta  = (const float*)d_in[1];
    const float* gamma = (const float*)d_in[2];
    float* out = (float*)d_out;

    const int H = in_sizes[0];                       // 16
    const long long ss = (long long)out_size / H;    // S*S
    const int S = (int)(sqrt((double)ss) + 0.5);     // 2048
    const int nrows = H * S;

    const int blocks = nrows < 2048 ? nrows : 2048;  // persistent, grid-stride
    bidirectional_alibi_kernel<<<blocks, 256, 0, stream>>>(alpha, beta, gamma, out, S, nrows);
}